// Round 7
// baseline (906.549 us; speedup 1.0000x reference)
//
#include <hip/hip_runtime.h>

typedef __attribute__((ext_vector_type(8))) short bf16x8;
typedef __attribute__((ext_vector_type(4))) float f32x4;
typedef __attribute__((ext_vector_type(2))) float f32x2;

static __device__ __forceinline__ unsigned short f2bf(float f) {
    union { float f; unsigned u; } v; v.f = f;
    return (unsigned short)((v.u + 0x7FFFu + ((v.u >> 16) & 1u)) >> 16);
}

// Wp[ch=4][rs=9][oc=256][cw=32] bf16, value = weight[oc][ch*32+cw][r][s] * wscale
__global__ void prep_weights(const float* __restrict__ w, unsigned short* __restrict__ wp) {
    int t = blockIdx.x * 256 + threadIdx.x;      // 0..294911
    const float wscale = 0.02946278254943948f;   // 1/sqrt(3*3*128)
    int cw = t & 31;
    int oc = (t >> 5) & 255;
    int cr = t >> 13;          // 0..35
    int ch = cr / 9;
    int rs = cr - ch * 9;
    int r  = rs / 3;
    int s  = rs - r * 3;
    int c  = ch * 32 + cw;
    wp[t] = f2bf(w[((oc * 128 + c) * 3 + r) * 3 + s] * wscale);
}

// ================= producer (blur) macros =================
// fast row: unconditional clamped 24B loads x2 planes, validity folded into rm
#define PXROW(ROW) {                                                           \
    int _xr = xr0 + (ROW);                                                     \
    int _xc = _xr < 0 ? 0 : (_xr > 255 ? 255 : _xr);                           \
    float _rm = (_xr == _xc) ? 0.125f : 0.0f;                                  \
    const float* _p0 = pq0 + (_xc << 8);                                       \
    const float* _p1 = pq1 + (_xc << 8);                                       \
    f32x4 _l0, _l1; f32x2 _h0, _h1;                                            \
    __builtin_memcpy(&_l0, _p0, 16); __builtin_memcpy(&_h0, _p0 + 4, 8);       \
    __builtin_memcpy(&_l1, _p1, 16); __builtin_memcpy(&_h1, _p1 + 4, 8);       \
    hA0[(ROW) & 3] = (_l0.x + 3.f * (_l0.y + _l0.z) + _l0.w) * _rm;            \
    hB0[(ROW) & 3] = (_l0.y + 3.f * (_l0.z + _l0.w) + _h0.x) * _rm;            \
    hC0[(ROW) & 3] = (_l0.z + 3.f * (_l0.w + _h0.x) + _h0.y) * _rm;            \
    hA1[(ROW) & 3] = (_l1.x + 3.f * (_l1.y + _l1.z) + _l1.w) * _rm;            \
    hB1[(ROW) & 3] = (_l1.y + 3.f * (_l1.z + _l1.w) + _h1.x) * _rm;            \
    hC1[(ROW) & 3] = (_l1.z + 3.f * (_l1.w + _h1.x) + _h1.y) * _rm;            \
}
// slow row (edge lanes): per-element guards
#define PSROW(ROW) {                                                           \
    int _xr = xr0 + (ROW);                                                     \
    float a0=0.f,a1=0.f,a2=0.f,a3=0.f,a4=0.f,a5=0.f;                           \
    float b0=0.f,b1=0.f,b2=0.f,b3=0.f,b4=0.f,b5=0.f;                           \
    if ((unsigned)_xr < 256u) {                                                \
        const float* _p0 = pq0 + (_xr << 8);                                   \
        const float* _p1 = pq1 + (_xr << 8);                                   \
        if ((unsigned)(wc + 0) < 256u) { a0 = _p0[0]; b0 = _p1[0]; }           \
        if ((unsigned)(wc + 1) < 256u) { a1 = _p0[1]; b1 = _p1[1]; }           \
        if ((unsigned)(wc + 2) < 256u) { a2 = _p0[2]; b2 = _p1[2]; }           \
        if ((unsigned)(wc + 3) < 256u) { a3 = _p0[3]; b3 = _p1[3]; }           \
        if ((unsigned)(wc + 4) < 256u) { a4 = _p0[4]; b4 = _p1[4]; }           \
        if ((unsigned)(wc + 5) < 256u) { a5 = _p0[5]; b5 = _p1[5]; }           \
    }                                                                          \
    hA0[(ROW) & 3] = (a0 + 3.f * (a1 + a2) + a3) * 0.125f;                     \
    hB0[(ROW) & 3] = (a1 + 3.f * (a2 + a3) + a4) * 0.125f;                     \
    hC0[(ROW) & 3] = (a2 + 3.f * (a3 + a4) + a5) * 0.125f;                     \
    hA1[(ROW) & 3] = (b0 + 3.f * (b1 + b2) + b3) * 0.125f;                     \
    hB1[(ROW) & 3] = (b1 + 3.f * (b2 + b3) + b4) * 0.125f;                     \
    hC1[(ROW) & 3] = (b2 + 3.f * (b3 + b4) + b5) * 0.125f;                     \
}
// vertical blur + packed u32 LDS writes (2 channels per write)
#define PVROW(ROW, BUFIMM) {                                                   \
    float vA0 = (hA0[(ROW-3)&3] + 3.f*(hA0[(ROW-2)&3]+hA0[(ROW-1)&3]) + hA0[(ROW)&3]) * 0.125f; \
    float vA1 = (hA1[(ROW-3)&3] + 3.f*(hA1[(ROW-2)&3]+hA1[(ROW-1)&3]) + hA1[(ROW)&3]) * 0.125f; \
    float vB0 = (hB0[(ROW-3)&3] + 3.f*(hB0[(ROW-2)&3]+hB0[(ROW-1)&3]) + hB0[(ROW)&3]) * 0.125f; \
    float vB1 = (hB1[(ROW-3)&3] + 3.f*(hB1[(ROW-2)&3]+hB1[(ROW-1)&3]) + hB1[(ROW)&3]) * 0.125f; \
    unsigned _rb = (BUFIMM) + (ROW - 3) * 2640u;                               \
    *(unsigned*)(lds + _rb + o0) = (unsigned)f2bf(vA0) | ((unsigned)f2bf(vA1) << 16); \
    *(unsigned*)(lds + _rb + o1) = (unsigned)f2bf(vB0) | ((unsigned)f2bf(vB1) << 16); \
    if (a15) {                                                                 \
        float vC0 = (hC0[(ROW-3)&3] + 3.f*(hC0[(ROW-2)&3]+hC0[(ROW-1)&3]) + hC0[(ROW)&3]) * 0.125f; \
        float vC1 = (hC1[(ROW-3)&3] + 3.f*(hC1[(ROW-2)&3]+hC1[(ROW-1)&3]) + hC1[(ROW)&3]) * 0.125f; \
        *(unsigned*)(lds + _rb + o2) = (unsigned)f2bf(vC0) | ((unsigned)f2bf(vC1) << 16); \
    }                                                                          \
}
#define PFP(ROW, BUFIMM) PXROW(ROW) PVROW(ROW, BUFIMM)
#define PSP(ROW, BUFIMM) PSROW(ROW) PVROW(ROW, BUFIMM)
#define PBLUR(CH, BUFIMM) {                                                    \
    const float* pq0 = pbx + (size_t)(CH) * 2097152;                           \
    const float* pq1 = pq0 + 65536;                                            \
    float hA0[4], hB0[4], hC0[4], hA1[4], hB1[4], hC1[4];                      \
    if (!edge) {                                                               \
        PXROW(0) PXROW(1) PXROW(2)                                             \
        PFP(3, BUFIMM)  PFP(4, BUFIMM)  PFP(5, BUFIMM)  PFP(6, BUFIMM)         \
        PFP(7, BUFIMM)  PFP(8, BUFIMM)  PFP(9, BUFIMM)  PFP(10, BUFIMM)        \
        PFP(11, BUFIMM) PFP(12, BUFIMM) PFP(13, BUFIMM) PFP(14, BUFIMM)        \
        PFP(15, BUFIMM) PFP(16, BUFIMM) PFP(17, BUFIMM) PFP(18, BUFIMM)        \
        PFP(19, BUFIMM)                                                        \
    } else {                                                                   \
        PSROW(0) PSROW(1) PSROW(2)                                             \
        PSP(3, BUFIMM)  PSP(4, BUFIMM)  PSP(5, BUFIMM)  PSP(6, BUFIMM)         \
        PSP(7, BUFIMM)  PSP(8, BUFIMM)  PSP(9, BUFIMM)  PSP(10, BUFIMM)        \
        PSP(11, BUFIMM) PSP(12, BUFIMM) PSP(13, BUFIMM) PSP(14, BUFIMM)        \
        PSP(15, BUFIMM) PSP(16, BUFIMM) PSP(17, BUFIMM) PSP(18, BUFIMM)        \
        PSP(19, BUFIMM)                                                        \
    } }

// ================= consumer (MFMA) macros =================
#define MF __builtin_amdgcn_mfma_f32_16x16x32_bf16
#define CSTEP(BUFIMM, ADRV, R, S0, S1, S2, S3) {                               \
    const unsigned char* _ab = lds + (BUFIMM) + (ADRV) + (R) * 2640;           \
    bf16x8 a0 = *(const bf16x8*)(_ab);                                         \
    bf16x8 a1 = *(const bf16x8*)(_ab +  5280);                                 \
    bf16x8 a2 = *(const bf16x8*)(_ab + 10560);                                 \
    bf16x8 a3 = *(const bf16x8*)(_ab + 15840);                                 \
    bf16x8 a4 = *(const bf16x8*)(_ab + 21120);                                 \
    bf16x8 a5 = *(const bf16x8*)(_ab + 26400);                                 \
    bf16x8 a6 = *(const bf16x8*)(_ab + 31680);                                 \
    bf16x8 a7 = *(const bf16x8*)(_ab + 36960);                                 \
    __builtin_amdgcn_s_setprio(1);                                             \
    acc[0][0]=MF(a0,S0,acc[0][0],0,0,0); acc[0][1]=MF(a0,S1,acc[0][1],0,0,0);  \
    acc[0][2]=MF(a0,S2,acc[0][2],0,0,0); acc[0][3]=MF(a0,S3,acc[0][3],0,0,0);  \
    acc[1][0]=MF(a1,S0,acc[1][0],0,0,0); acc[1][1]=MF(a1,S1,acc[1][1],0,0,0);  \
    acc[1][2]=MF(a1,S2,acc[1][2],0,0,0); acc[1][3]=MF(a1,S3,acc[1][3],0,0,0);  \
    acc[2][0]=MF(a2,S0,acc[2][0],0,0,0); acc[2][1]=MF(a2,S1,acc[2][1],0,0,0);  \
    acc[2][2]=MF(a2,S2,acc[2][2],0,0,0); acc[2][3]=MF(a2,S3,acc[2][3],0,0,0);  \
    acc[3][0]=MF(a3,S0,acc[3][0],0,0,0); acc[3][1]=MF(a3,S1,acc[3][1],0,0,0);  \
    acc[3][2]=MF(a3,S2,acc[3][2],0,0,0); acc[3][3]=MF(a3,S3,acc[3][3],0,0,0);  \
    acc[4][0]=MF(a4,S0,acc[4][0],0,0,0); acc[4][1]=MF(a4,S1,acc[4][1],0,0,0);  \
    acc[4][2]=MF(a4,S2,acc[4][2],0,0,0); acc[4][3]=MF(a4,S3,acc[4][3],0,0,0);  \
    acc[5][0]=MF(a5,S0,acc[5][0],0,0,0); acc[5][1]=MF(a5,S1,acc[5][1],0,0,0);  \
    acc[5][2]=MF(a5,S2,acc[5][2],0,0,0); acc[5][3]=MF(a5,S3,acc[5][3],0,0,0);  \
    acc[6][0]=MF(a6,S0,acc[6][0],0,0,0); acc[6][1]=MF(a6,S1,acc[6][1],0,0,0);  \
    acc[6][2]=MF(a6,S2,acc[6][2],0,0,0); acc[6][3]=MF(a6,S3,acc[6][3],0,0,0);  \
    acc[7][0]=MF(a7,S0,acc[7][0],0,0,0); acc[7][1]=MF(a7,S1,acc[7][1],0,0,0);  \
    acc[7][2]=MF(a7,S2,acc[7][2],0,0,0); acc[7][3]=MF(a7,S3,acc[7][3],0,0,0);  \
    __builtin_amdgcn_s_setprio(0);                                             \
}
#define WLOAD(S0, S1, S2, S3, KOFF) {                                          \
    const unsigned short* _wn = wbase + (size_t)(KOFF) * 8192;                 \
    S0 = *(const bf16x8*)(_wn);        S1 = *(const bf16x8*)(_wn + 512);       \
    S2 = *(const bf16x8*)(_wn + 1024); S3 = *(const bf16x8*)(_wn + 1536);      \
}
#define CHUNK(BUFIMM, A0,A1,A2,A3, B0,B1,B2,B3, BASE)                          \
    CSTEP(BUFIMM, adr0, 0, A0,A1,A2,A3) WLOAD(A0,A1,A2,A3, (BASE)+2)           \
    CSTEP(BUFIMM, adr1, 0, B0,B1,B2,B3) WLOAD(B0,B1,B2,B3, (BASE)+3)           \
    CSTEP(BUFIMM, adr2, 0, A0,A1,A2,A3) WLOAD(A0,A1,A2,A3, (BASE)+4)           \
    CSTEP(BUFIMM, adr0, 1, B0,B1,B2,B3) WLOAD(B0,B1,B2,B3, (BASE)+5)           \
    CSTEP(BUFIMM, adr1, 1, A0,A1,A2,A3) WLOAD(A0,A1,A2,A3, (BASE)+6)           \
    CSTEP(BUFIMM, adr2, 1, B0,B1,B2,B3) WLOAD(B0,B1,B2,B3, (BASE)+7)           \
    CSTEP(BUFIMM, adr0, 2, A0,A1,A2,A3) WLOAD(A0,A1,A2,A3, (BASE)+8)           \
    CSTEP(BUFIMM, adr1, 2, B0,B1,B2,B3) WLOAD(B0,B1,B2,B3, (BASE)+9)           \
    CSTEP(BUFIMM, adr2, 2, A0,A1,A2,A3) WLOAD(A0,A1,A2,A3, (BASE)+10)
#define CHUNK_LAST(BUFIMM, A0,A1,A2,A3, B0,B1,B2,B3, BASE)                     \
    CSTEP(BUFIMM, adr0, 0, A0,A1,A2,A3) WLOAD(A0,A1,A2,A3, (BASE)+2)           \
    CSTEP(BUFIMM, adr1, 0, B0,B1,B2,B3) WLOAD(B0,B1,B2,B3, (BASE)+3)           \
    CSTEP(BUFIMM, adr2, 0, A0,A1,A2,A3) WLOAD(A0,A1,A2,A3, (BASE)+4)           \
    CSTEP(BUFIMM, adr0, 1, B0,B1,B2,B3) WLOAD(B0,B1,B2,B3, (BASE)+5)           \
    CSTEP(BUFIMM, adr1, 1, A0,A1,A2,A3) WLOAD(A0,A1,A2,A3, (BASE)+6)           \
    CSTEP(BUFIMM, adr2, 1, B0,B1,B2,B3) WLOAD(B0,B1,B2,B3, (BASE)+7)           \
    CSTEP(BUFIMM, adr0, 2, A0,A1,A2,A3) WLOAD(A0,A1,A2,A3, (BASE)+8)           \
    CSTEP(BUFIMM, adr1, 2, B0,B1,B2,B3)                                        \
    CSTEP(BUFIMM, adr2, 2, A0,A1,A2,A3)

// block = 512 thr = 8 waves: waves 0-3 consumers (MFMA, 64 oc each),
// waves 4-7 producers (blur). Tile = 8h x 16w out px x 256 oc.
// LDS: double-buffered blurred tile [17][33] px x 80 B (XOR-swizzled ch slots).
__global__ __launch_bounds__(512, 2)
void conv_blur_mfma(const float* __restrict__ x, const unsigned short* __restrict__ wp,
                    const float* __restrict__ bias, float* __restrict__ out) {
    __shared__ __align__(16) unsigned char lds[2 * 44880];

    // bijective XCD swizzle: each XCD runs the 8 v-tiles of a band consecutively
    const int d    = blockIdx.x;                  // 0..2047
    const int band = (d & 7) | ((d >> 6) << 3);   // 0..255
    const int n    = band >> 4;
    const int u0   = (band & 15) * 8;
    const int v0   = ((d >> 3) & 7) * 16;

    const int tid  = threadIdx.x;
    const int lane = tid & 63;
    const int wid  = tid >> 6;
    const bool consumer = (wid < 4);
    const int g    = lane >> 4;
    const int wq   = lane & 15;

    // ---- producer indices (waves 4-7) ----
    const int ptid = tid & 255;
    const int cp   = ptid >> 4;          // channel pair 0..15 (chs 2cp, 2cp+1)
    const int a    = ptid & 15;          // col pair -> blurred cols 2a, 2a+1 (+32 if a==15)
    const bool a15 = (a == 15);
    const int wc   = 2 * v0 - 2 + 2 * a;
    const bool edge = (v0 == 0 && a == 0) || (v0 == 112 && a15);
    const float* pbx = x + (size_t)(n * 128 + 2 * cp) * 65536 + wc;
    const int xr0 = 2 * u0 - 2;
    const unsigned q4 = (unsigned)(cp >> 2);
    const unsigned cb = (unsigned)(cp & 3) * 4u;
    const int c0 = 2 * a;
    const unsigned o0 = (unsigned)(c0+0)*80u + ((q4 ^ (((unsigned)(c0+0) >> 3) & 3u)) << 4) + cb;
    const unsigned o1 = (unsigned)(c0+1)*80u + ((q4 ^ (((unsigned)(c0+1) >> 3) & 3u)) << 4) + cb;
    const unsigned o2 = 32u*80u + (q4 << 4) + cb;

    // ---- consumer state (waves 0-3) ----
    const unsigned short* wbase = wp + (size_t)(wid * 64 + wq) * 32 + g * 8;
    const unsigned adr0 = (2u*wq + 0u)*80u + (((unsigned)g ^ (((2u*wq + 0u) >> 3) & 3u)) << 4);
    const unsigned adr1 = (2u*wq + 1u)*80u + (((unsigned)g ^ (((2u*wq + 1u) >> 3) & 3u)) << 4);
    const unsigned adr2 = (2u*wq + 2u)*80u + (((unsigned)g ^ (((2u*wq + 2u) >> 3) & 3u)) << 4);

    f32x4 acc[8][4];
    bf16x8 WA0, WA1, WA2, WA3, WB0, WB1, WB2, WB3;

    if (consumer) {
        #pragma unroll
        for (int i = 0; i < 8; ++i)
            #pragma unroll
            for (int j = 0; j < 4; ++j)
                acc[i][j] = (f32x4){0.f, 0.f, 0.f, 0.f};
        WLOAD(WA0, WA1, WA2, WA3, 0)
        WLOAD(WB0, WB1, WB2, WB3, 1)
    } else {
        PBLUR(0, 0)
    }
    __syncthreads();
    if (consumer) { CHUNK(0,     WA0,WA1,WA2,WA3, WB0,WB1,WB2,WB3, 0)  }
    else          { PBLUR(1, 44880) }
    __syncthreads();
    if (consumer) { CHUNK(44880, WB0,WB1,WB2,WB3, WA0,WA1,WA2,WA3, 9)  }
    else          { PBLUR(2, 0) }
    __syncthreads();
    if (consumer) { CHUNK(0,     WA0,WA1,WA2,WA3, WB0,WB1,WB2,WB3, 18) }
    else          { PBLUR(3, 44880) }
    __syncthreads();
    if (consumer) {
        CHUNK_LAST(44880, WB0,WB1,WB2,WB3, WA0,WA1,WA2,WA3, 27)
        // epilogue: u = u0 + mf, v = v0 + 4g + i, oc = wid*64 + nf*16 + wq
        const float gain = 1.4142135623730951f;
        #pragma unroll
        for (int nf = 0; nf < 4; ++nf) {
            const int ocg = wid * 64 + nf * 16 + wq;
            const float bb = bias[ocg];          // LR_MUL = 1
            #pragma unroll
            for (int mf = 0; mf < 8; ++mf) {
                f32x4 o;
                #pragma unroll
                for (int i = 0; i < 4; ++i) {
                    float z = acc[mf][nf][i] + bb;
                    z = (z >= 0.f ? z : 0.2f * z) * gain;
                    o[i] = fminf(fmaxf(z, -256.f), 256.f);
                }
                *(f32x4*)(out + (((size_t)n * 256 + ocg) * 128 + (u0 + mf)) * 128 + v0 + 4 * g) = o;
            }
        }
    }
}

extern "C" void kernel_launch(void* const* d_in, const int* in_sizes, int n_in,
                              void* d_out, int out_size, void* d_ws, size_t ws_size,
                              hipStream_t stream) {
    const float* x    = (const float*)d_in[0];
    const float* w    = (const float*)d_in[1];
    const float* bias = (const float*)d_in[2];
    unsigned short* wp = (unsigned short*)d_ws;   // 589,824 B
    float* out = (float*)d_out;

    prep_weights<<<1152, 256, 0, stream>>>(w, wp);
    conv_blur_mfma<<<2048, 512, 0, stream>>>(x, wp, bias, out);
}

// Round 8
// 563.226 us; speedup vs baseline: 1.6096x; 1.6096x over previous
//
#include <hip/hip_runtime.h>

typedef __attribute__((ext_vector_type(8))) short bf16x8;
typedef __attribute__((ext_vector_type(4))) float f32x4;
typedef __attribute__((ext_vector_type(2))) float f32x2;
typedef __attribute__((ext_vector_type(4))) unsigned int u32x4;

static __device__ __forceinline__ unsigned short f2bf(float f) {
    union { float f; unsigned u; } v; v.f = f;
    return (unsigned short)((v.u + 0x7FFFu + ((v.u >> 16) & 1u)) >> 16);
}

// Wp[ch=4][rs=9][oc=256][cw=32] bf16, value = weight[oc][ch*32+cw][r][s] * wscale
__global__ void prep_weights(const float* __restrict__ w, unsigned short* __restrict__ wp) {
    int t = blockIdx.x * 256 + threadIdx.x;      // 0..294911
    const float wscale = 0.02946278254943948f;   // 1/sqrt(3*3*128)
    int cw = t & 31;
    int oc = (t >> 5) & 255;
    int cr = t >> 13;          // 0..35
    int ch = cr / 9;
    int rs = cr - ch * 9;
    int r  = rs / 3;
    int s  = rs - r * 3;
    int c  = ch * 32 + cw;
    wp[t] = f2bf(w[((oc * 128 + c) * 3 + r) * 3 + s] * wscale);
}

// ======================= Split path =======================
// Blurred tensor in d_ws: [n][cg=4][t:258][row = 258 granules x 64B]
//   granule (t, J) holds 32 ch bf16 of blurred px; within-row granule position
//   Jsw = J ^ ((J>>1)&1); within granule, 16B slot = (c>>3) ^ ((J>>2)&3), byte (c&7)*2.
//   (Swizzle chosen so stage-2's stride-2 ds_read_b128 is bank-conflict-free.)
// B(t,J) = sum_{p,q} f[p]f[q] x[t-2+p][J-2+q], f = {1,3,3,1}/8, zero OOB. t,J in 0..256.

__global__ void blur_pre(const float* __restrict__ x, unsigned char* __restrict__ bl) {
    const int b   = blockIdx.x;
    const int tid = threadIdx.x;
    const int c   = tid & 31;
    if (b < 64) {
        // edge blocks (scheduled first): col J=256 for all t, and row t=256 for J 0..255
        const int n = b >> 2, cg = b & 3;
        const float* xp = x + (size_t)(n * 128 + cg * 32 + c) * 65536;
        unsigned char* ob = bl + (size_t)(n * 4 + cg) * 4260096;
        const int eb = tid >> 5;
        const float fw0 = 1.f, fw1 = 3.f, fw2 = 3.f, fw3 = 1.f;
        for (int e = eb; e < 513; e += 8) {
            int t, J;
            if (e < 257) { t = e; J = 256; } else { t = 256; J = e - 257; }
            float acc = 0.f;
            #pragma unroll
            for (int p = 0; p < 4; ++p) {
                int xr = t - 2 + p;
                if ((unsigned)xr < 256u) {
                    const float* rp = xp + (xr << 8);
                    float fp = (p == 0) ? fw0 : (p == 1) ? fw1 : (p == 2) ? fw2 : fw3;
                    #pragma unroll
                    for (int q = 0; q < 4; ++q) {
                        int xc = J - 2 + q;
                        float fq = (q == 0) ? fw0 : (q == 1) ? fw1 : (q == 2) ? fw2 : fw3;
                        if ((unsigned)xc < 256u) acc += fp * fq * rp[xc];
                    }
                }
            }
            acc *= 0.015625f;   // 1/64
            unsigned off = (unsigned)(J ^ ((J >> 1) & 1)) * 64u
                         + ((unsigned)((c >> 3) ^ ((J >> 2) & 3)) << 4) + (unsigned)(c & 7) * 2u;
            *(unsigned short*)(ob + (size_t)t * 16512 + off) = f2bf(acc);
        }
        return;
    }
    // main blocks: tile = 16 t-rows x 64 cols x 32 ch (one cg chunk)
    const int b2 = b - 64;
    const int tband = b2 & 15, band = (b2 >> 4) & 3, cg = (b2 >> 6) & 3, n = b2 >> 8;
    const int cb = tid >> 5;
    const int J0 = band * 64 + cb * 8;
    const int t0 = tband * 16;
    const bool edge = (J0 == 0) || (J0 == 248);
    const float* xp = x + (size_t)(n * 128 + cg * 32 + c) * 65536;
    unsigned char* ob = bl + (size_t)(n * 4 + cg) * 4260096;
    unsigned off[8];
    #pragma unroll
    for (int j = 0; j < 8; ++j) {
        int J = J0 + j;
        off[j] = (unsigned)(J ^ ((J >> 1) & 1)) * 64u
               + ((unsigned)((c >> 3) ^ ((J >> 2) & 3)) << 4) + (unsigned)(c & 7) * 2u;
    }
    float h[8][4];
    #pragma unroll
    for (int i = 0; i < 19; ++i) {
        int xr = t0 - 2 + i;
        if (!edge) {
            int xc = xr < 0 ? 0 : (xr > 255 ? 255 : xr);
            float rm = (xr == xc) ? 0.125f : 0.f;
            const float* p = xp + (xc << 8) + (J0 - 2);
            f32x4 w0, w1, w2;
            __builtin_memcpy(&w0, p, 16);
            __builtin_memcpy(&w1, p + 4, 16);
            __builtin_memcpy(&w2, p + 8, 16);
            float wv[12] = {w0.x, w0.y, w0.z, w0.w, w1.x, w1.y, w1.z, w1.w,
                            w2.x, w2.y, w2.z, w2.w};
            #pragma unroll
            for (int j = 0; j < 8; ++j)
                h[j][i & 3] = (wv[j] + 3.f * (wv[j + 1] + wv[j + 2]) + wv[j + 3]) * rm;
        } else {
            float wv[12];
            #pragma unroll
            for (int m = 0; m < 12; ++m) {
                int xc2 = J0 - 2 + m;
                wv[m] = ((unsigned)xr < 256u && (unsigned)xc2 < 256u)
                        ? xp[(xr << 8) + xc2] : 0.f;
            }
            #pragma unroll
            for (int j = 0; j < 8; ++j)
                h[j][i & 3] = (wv[j] + 3.f * (wv[j + 1] + wv[j + 2]) + wv[j + 3]) * 0.125f;
        }
        if (i >= 3) {
            unsigned char* rowp = ob + (size_t)(t0 + i - 3) * 16512;
            #pragma unroll
            for (int j = 0; j < 8; ++j) {
                float B = (h[j][(i - 3) & 3] + 3.f * (h[j][(i - 2) & 3] + h[j][(i - 1) & 3])
                           + h[j][i & 3]) * 0.125f;
                *(unsigned short*)(rowp + off[j]) = f2bf(B);
            }
        }
    }
}

// ---------------- stage 2: MFMA conv over blurred ----------------
#define MF __builtin_amdgcn_mfma_f32_16x16x32_bf16
#define WLOAD(S0, S1, S2, S3, KOFF) {                                          \
    const unsigned short* _wn = wbase + (size_t)(KOFF) * 8192;                 \
    S0 = *(const bf16x8*)(_wn);        S1 = *(const bf16x8*)(_wn + 512);       \
    S2 = *(const bf16x8*)(_wn + 1024); S3 = *(const bf16x8*)(_wn + 1536);      \
}
#define CSTEP(ADRS, R, S0, S1, S2, S3) {                                       \
    const unsigned char* _ab = lds + (ADRS) + (R) * 2112;                      \
    bf16x8 a0 = *(const bf16x8*)(_ab);                                         \
    bf16x8 a1 = *(const bf16x8*)(_ab + 4224);                                  \
    bf16x8 a2 = *(const bf16x8*)(_ab + 8448);                                  \
    bf16x8 a3 = *(const bf16x8*)(_ab + 12672);                                 \
    __builtin_amdgcn_s_setprio(1);                                             \
    acc[0][0]=MF(a0,S0,acc[0][0],0,0,0); acc[0][1]=MF(a0,S1,acc[0][1],0,0,0);  \
    acc[0][2]=MF(a0,S2,acc[0][2],0,0,0); acc[0][3]=MF(a0,S3,acc[0][3],0,0,0);  \
    acc[1][0]=MF(a1,S0,acc[1][0],0,0,0); acc[1][1]=MF(a1,S1,acc[1][1],0,0,0);  \
    acc[1][2]=MF(a1,S2,acc[1][2],0,0,0); acc[1][3]=MF(a1,S3,acc[1][3],0,0,0);  \
    acc[2][0]=MF(a2,S0,acc[2][0],0,0,0); acc[2][1]=MF(a2,S1,acc[2][1],0,0,0);  \
    acc[2][2]=MF(a2,S2,acc[2][2],0,0,0); acc[2][3]=MF(a2,S3,acc[2][3],0,0,0);  \
    acc[3][0]=MF(a3,S0,acc[3][0],0,0,0); acc[3][1]=MF(a3,S1,acc[3][1],0,0,0);  \
    acc[3][2]=MF(a3,S2,acc[3][2],0,0,0); acc[3][3]=MF(a3,S3,acc[3][3],0,0,0);  \
    __builtin_amdgcn_s_setprio(0);                                             \
}
#define CHUNK(BASE, A0,A1,A2,A3, B0,B1,B2,B3)                                  \
    CSTEP(adr0, 0, A0,A1,A2,A3) WLOAD(A0,A1,A2,A3, (BASE)+2)                   \
    CSTEP(adr1, 0, B0,B1,B2,B3) WLOAD(B0,B1,B2,B3, (BASE)+3)                   \
    CSTEP(adr2, 0, A0,A1,A2,A3) WLOAD(A0,A1,A2,A3, (BASE)+4)                   \
    CSTEP(adr0, 1, B0,B1,B2,B3) WLOAD(B0,B1,B2,B3, (BASE)+5)                   \
    CSTEP(adr1, 1, A0,A1,A2,A3) WLOAD(A0,A1,A2,A3, (BASE)+6)                   \
    CSTEP(adr2, 1, B0,B1,B2,B3) WLOAD(B0,B1,B2,B3, (BASE)+7)                   \
    CSTEP(adr0, 2, A0,A1,A2,A3) WLOAD(A0,A1,A2,A3, (BASE)+8)                   \
    CSTEP(adr1, 2, B0,B1,B2,B3) WLOAD(B0,B1,B2,B3, (BASE)+9)                   \
    CSTEP(adr2, 2, A0,A1,A2,A3) WLOAD(A0,A1,A2,A3, (BASE)+10)
#define CHUNK_LAST(BASE, A0,A1,A2,A3, B0,B1,B2,B3)                             \
    CSTEP(adr0, 0, A0,A1,A2,A3) WLOAD(A0,A1,A2,A3, (BASE)+2)                   \
    CSTEP(adr1, 0, B0,B1,B2,B3) WLOAD(B0,B1,B2,B3, (BASE)+3)                   \
    CSTEP(adr2, 0, A0,A1,A2,A3) WLOAD(A0,A1,A2,A3, (BASE)+4)                   \
    CSTEP(adr0, 1, B0,B1,B2,B3) WLOAD(B0,B1,B2,B3, (BASE)+5)                   \
    CSTEP(adr1, 1, A0,A1,A2,A3) WLOAD(A0,A1,A2,A3, (BASE)+6)                   \
    CSTEP(adr2, 1, B0,B1,B2,B3) WLOAD(B0,B1,B2,B3, (BASE)+7)                   \
    CSTEP(adr0, 2, A0,A1,A2,A3) WLOAD(A0,A1,A2,A3, (BASE)+8)                   \
    CSTEP(adr1, 2, B0,B1,B2,B3)                                                \
    CSTEP(adr2, 2, A0,A1,A2,A3)

// 512 thr = 8 waves (2m x 4n), out tile 8u x 16v x 256 oc. A-tile (17 rows x 33
// granules = 35904 B) copied blurred->regs->LDS; next chunk's loads issued right
// after the tile barrier so they fly under the MFMA phase (T14).
__global__ __launch_bounds__(512, 3)
void conv_stage2(const unsigned char* __restrict__ bl, const unsigned short* __restrict__ wp,
                 const float* __restrict__ bias, float* __restrict__ out) {
    __shared__ __align__(16) unsigned char lds[35904];

    const int bx = blockIdx.x;
    const int n  = bx >> 7;
    const int tt = bx & 127;
    const int u0 = (tt >> 3) * 8;
    const int v0 = (tt & 7) * 16;

    const int tid  = threadIdx.x;
    const int lane = tid & 63;
    const int wid  = tid >> 6;
    const int wm   = wid >> 2;       // 0..1
    const int wn   = wid & 3;        // 0..3
    const int g    = lane >> 4;
    const int wq   = lane & 15;

    // staging slot geometry: 2244 16B-slots = 17 rows x 132
    unsigned goff[5];
    #pragma unroll
    for (int k = 0; k < 5; ++k) {
        int sl  = tid + 512 * k;
        int row = sl / 132;
        int cs  = sl - row * 132;
        goff[k] = (unsigned)(2 * u0 + row) * 16512u + (unsigned)v0 * 128u + (unsigned)cs * 16u;
    }
    const bool v4 = (tid < 196);
    const unsigned char* gb = bl + (size_t)n * 4 * 4260096;

    // A-frag LDS base per s (granule+slot swizzle matches blur_pre's layout)
    unsigned adr0, adr1, adr2;
    {
        #pragma unroll
        for (int s = 0; s < 3; ++s) {
            unsigned bj = 2u * (unsigned)wq + (unsigned)s;
            unsigned av = (bj ^ ((bj >> 1) & 1u)) * 64u
                        + (((unsigned)g ^ ((bj >> 2) & 3u)) << 4) + (unsigned)wm * 16896u;
            if (s == 0) adr0 = av; else if (s == 1) adr1 = av; else adr2 = av;
        }
    }

    const unsigned short* wbase = wp + (size_t)(wn * 64 + wq) * 32 + g * 8;
    bf16x8 WA0, WA1, WA2, WA3, WB0, WB1, WB2, WB3;
    WLOAD(WA0, WA1, WA2, WA3, 0)
    WLOAD(WB0, WB1, WB2, WB3, 1)

    f32x4 acc[4][4];
    #pragma unroll
    for (int i = 0; i < 4; ++i)
        #pragma unroll
        for (int j = 0; j < 4; ++j)
            acc[i][j] = (f32x4){0.f, 0.f, 0.f, 0.f};

    // prologue: load chunk 0 into regs
    u32x4 L0, L1, L2, L3, L4 = (u32x4){0u, 0u, 0u, 0u};
    {
        const unsigned char* g0 = gb;
        L0 = *(const u32x4*)(g0 + goff[0]);
        L1 = *(const u32x4*)(g0 + goff[1]);
        L2 = *(const u32x4*)(g0 + goff[2]);
        L3 = *(const u32x4*)(g0 + goff[3]);
        if (v4) L4 = *(const u32x4*)(g0 + goff[4]);
    }
    const unsigned lb = (unsigned)tid * 16u;

#define STAGE_WRITE() {                                                        \
    *(u32x4*)(lds + lb)          = L0;                                         \
    *(u32x4*)(lds + lb + 8192)   = L1;                                         \
    *(u32x4*)(lds + lb + 16384)  = L2;                                         \
    *(u32x4*)(lds + lb + 24576)  = L3;                                         \
    if (v4) *(u32x4*)(lds + lb + 32768) = L4;                                  \
}
#define STAGE_LOAD(CGN) {                                                      \
    const unsigned char* _gn = gb + (size_t)(CGN) * 4260096;                   \
    L0 = *(const u32x4*)(_gn + goff[0]);                                       \
    L1 = *(const u32x4*)(_gn + goff[1]);                                       \
    L2 = *(const u32x4*)(_gn + goff[2]);                                       \
    L3 = *(const u32x4*)(_gn + goff[3]);                                       \
    if (v4) L4 = *(const u32x4*)(_gn + goff[4]);                               \
}

    // chunk 0
    STAGE_WRITE()
    __syncthreads();
    STAGE_LOAD(1)
    CHUNK(0, WA0, WA1, WA2, WA3, WB0, WB1, WB2, WB3)
    // chunk 1
    __syncthreads();
    STAGE_WRITE()
    __syncthreads();
    STAGE_LOAD(2)
    CHUNK(9, WB0, WB1, WB2, WB3, WA0, WA1, WA2, WA3)
    // chunk 2
    __syncthreads();
    STAGE_WRITE()
    __syncthreads();
    STAGE_LOAD(3)
    CHUNK(18, WA0, WA1, WA2, WA3, WB0, WB1, WB2, WB3)
    // chunk 3
    __syncthreads();
    STAGE_WRITE()
    __syncthreads();
    CHUNK_LAST(27, WB0, WB1, WB2, WB3, WA0, WA1, WA2, WA3)

    // epilogue: u = u0 + wm*4 + mf, v = v0 + 4g + i, oc = wn*64 + nf*16 + wq
    const float gain = 1.4142135623730951f;
    #pragma unroll
    for (int nf = 0; nf < 4; ++nf) {
        const int ocg = wn * 64 + nf * 16 + wq;
        const float bb = bias[ocg];
        #pragma unroll
        for (int mf = 0; mf < 4; ++mf) {
            int u = u0 + wm * 4 + mf;
            f32x4 o;
            #pragma unroll
            for (int i = 0; i < 4; ++i) {
                float z = acc[mf][nf][i] + bb;
                z = (z >= 0.f ? z : 0.2f * z) * gain;
                o[i] = fminf(fmaxf(z, -256.f), 256.f);
            }
            *(f32x4*)(out + (((size_t)n * 256 + ocg) * 128 + u) * 128 + v0 + 4 * g) = o;
        }
    }
}

// ======================= Fallback: proven R5 fused kernel =======================
#define FROW(row) {                                                            \
    int xr  = xr0 + (row);                                                     \
    int xrc = xr < 0 ? 0 : (xr > 255 ? 255 : xr);                              \
    float rm = (xr == xrc) ? 0.125f : 0.0f;                                    \
    const float* p = q + (xrc << 8);                                           \
    f32x4 lo; f32x2 hi;                                                        \
    __builtin_memcpy(&lo, p, 16);                                              \
    __builtin_memcpy(&hi, p + 4, 8);                                           \
    hA[(row) & 3] = (lo.x + 3.f * (lo.y + lo.z) + lo.w) * rm;                  \
    hB[(row) & 3] = (lo.y + 3.f * (lo.z + lo.w) + hi.x) * rm;                  \
    hC[(row) & 3] = (lo.z + 3.f * (lo.w + hi.x) + hi.y) * rm;                  \
}
#define SROW(row) {                                                            \
    int xr = xr0 + (row);                                                      \
    float wv0=0.f,wv1=0.f,wv2=0.f,wv3=0.f,wv4=0.f,wv5=0.f;                     \
    if ((unsigned)xr < 256u) {                                                 \
        const float* p = q + (xr << 8);                                        \
        if ((unsigned)(wc + 0) < 256u) wv0 = p[0];                             \
        if ((unsigned)(wc + 1) < 256u) wv1 = p[1];                             \
        if ((unsigned)(wc + 2) < 256u) wv2 = p[2];                             \
        if ((unsigned)(wc + 3) < 256u) wv3 = p[3];                             \
        if ((unsigned)(wc + 4) < 256u) wv4 = p[4];                             \
        if ((unsigned)(wc + 5) < 256u) wv5 = p[5];                             \
    }                                                                          \
    hA[(row) & 3] = (wv0 + 3.f * (wv1 + wv2) + wv3) * 0.125f;                  \
    hB[(row) & 3] = (wv1 + 3.f * (wv2 + wv3) + wv4) * 0.125f;                  \
    hC[(row) & 3] = (wv2 + 3.f * (wv3 + wv4) + wv5) * 0.125f;                  \
}
#define VROW(row) {                                                            \
    float bv0 = (hA[(row - 3) & 3] + 3.f * (hA[(row - 2) & 3] + hA[(row - 1) & 3]) + hA[(row) & 3]) * 0.125f; \
    float bv1 = (hB[(row - 3) & 3] + 3.f * (hB[(row - 2) & 3] + hB[(row - 1) & 3]) + hB[(row) & 3]) * 0.125f; \
    unsigned rb = (unsigned)(row - 3) * 2640u;                                 \
    *(unsigned short*)(flds + rb + o0) = f2bf(bv0);                            \
    *(unsigned short*)(flds + rb + o1) = f2bf(bv1);                            \
    if (a == 15) {                                                             \
        float bv2 = (hC[(row - 3) & 3] + 3.f * (hC[(row - 2) & 3] + hC[(row - 1) & 3]) + hC[(row) & 3]) * 0.125f; \
        *(unsigned short*)(flds + rb + o2) = f2bf(bv2);                        \
    }                                                                          \
}
__global__ __launch_bounds__(512, 4)
void conv_blur_mfma(const float* __restrict__ x, const unsigned short* __restrict__ wp,
                    const float* __restrict__ bias, float* __restrict__ out) {
    __shared__ __align__(16) unsigned char flds[17 * 33 * 80];
    const int bx = blockIdx.x;
    const int n  = bx >> 7;
    const int tt = bx & 127;
    const int u0 = (tt >> 3) * 8;
    const int v0 = (tt & 7) * 16;
    const int tid  = threadIdx.x;
    const int lane = tid & 63;
    const int wid  = tid >> 6;
    const int wm   = wid >> 2;
    const int wn   = wid & 3;
    const int g    = lane >> 4;
    const int wq   = lane & 15;
    const int a   = tid & 15;
    const int chl = tid >> 4;
    const int wc  = 2 * v0 - 2 + 2 * a;
    const bool edge = (v0 == 0 && a == 0) || (v0 == 112 && a == 15);
    const float* planeBase = x + (size_t)(n * 128 + chl) * 65536;
    const int xr0 = 2 * u0 - 2;
    const unsigned chpart = (unsigned)(((chl >> 1) & 3) * 4 + (chl & 1) * 2);
    const unsigned q4 = (unsigned)(chl >> 3);
    const int c0 = 2 * a;
    const unsigned o0 = (unsigned)(c0 + 0) * 80u + ((q4 ^ (((unsigned)(c0 + 0) >> 3) & 3u)) << 4) + chpart;
    const unsigned o1 = (unsigned)(c0 + 1) * 80u + ((q4 ^ (((unsigned)(c0 + 1) >> 3) & 3u)) << 4) + chpart;
    const unsigned o2 = (unsigned)(c0 + 2) * 80u + ((q4 ^ (((unsigned)(c0 + 2) >> 3) & 3u)) << 4) + chpart;
    const unsigned short* wpL = wp + (size_t)(wn * 64 + wq) * 32 + g * 8;
    f32x4 acc[4][4];
    #pragma unroll
    for (int i = 0; i < 4; ++i)
        #pragma unroll
        for (int j = 0; j < 4; ++j)
            acc[i][j] = (f32x4){0.f, 0.f, 0.f, 0.f};
    for (int ch = 0; ch < 4; ++ch) {
        const float* q = planeBase + (size_t)ch * 32 * 65536 + wc;
        float hA[4], hB[4], hC[4];
        if (!edge) { FROW(0) FROW(1) FROW(2) }
        else       { SROW(0) SROW(1) SROW(2) }
        __syncthreads();
        if (!edge) {
            #pragma unroll
            for (int row = 3; row < 20; ++row) { FROW(row) VROW(row) }
        } else {
            #pragma unroll
            for (int row = 3; row < 20; ++row) { SROW(row) VROW(row) }
        }
        __syncthreads();
        const unsigned short* wpc = wpL + (size_t)ch * 9 * 8192;
        #pragma unroll 1
        for (int r = 0; r < 3; ++r) {
            #pragma unroll 1
            for (int s = 0; s < 3; ++s) {
                bf16x8 b0 = *(const bf16x8*)(wpc + 0 * 512);
                bf16x8 b1 = *(const bf16x8*)(wpc + 1 * 512);
                bf16x8 b2 = *(const bf16x8*)(wpc + 2 * 512);
                bf16x8 b3 = *(const bf16x8*)(wpc + 3 * 512);
                wpc += 8192;
                int bj = 2 * wq + s;
                unsigned cb = (unsigned)bj * 80u + ((unsigned)(g ^ ((bj >> 3) & 3)) << 4);
                #pragma unroll
                for (int mf = 0; mf < 4; ++mf) {
                    int bi = 2 * (wm * 4 + mf) + r;
                    bf16x8 afrag = *(const bf16x8*)(flds + (unsigned)bi * 2640u + cb);
                    acc[mf][0] = MF(afrag, b0, acc[mf][0], 0, 0, 0);
                    acc[mf][1] = MF(afrag, b1, acc[mf][1], 0, 0, 0);
                    acc[mf][2] = MF(afrag, b2, acc[mf][2], 0, 0, 0);
                    acc[mf][3] = MF(afrag, b3, acc[mf][3], 0, 0, 0);
                }
            }
        }
    }
    const float gain = 1.4142135623730951f;
    #pragma unroll
    for (int nf = 0; nf < 4; ++nf) {
        int ocg = wn * 64 + nf * 16 + wq;
        float bv = bias[ocg];
        #pragma unroll
        for (int mf = 0; mf < 4; ++mf) {
            int u = u0 + wm * 4 + mf;
            f32x4 o;
            #pragma unroll
            for (int i = 0; i < 4; ++i) {
                float z = acc[mf][nf][i] + bv;
                z = (z >= 0.f ? z : 0.2f * z) * gain;
                o[i] = fminf(fmaxf(z, -256.f), 256.f);
            }
            *(f32x4*)(out + (((size_t)n * 256 + ocg) * 128 + u) * 128 + v0 + 4 * g) = o;
        }
    }
}

extern "C" void kernel_launch(void* const* d_in, const int* in_sizes, int n_in,
                              void* d_out, int out_size, void* d_ws, size_t ws_size,
                              hipStream_t stream) {
    const float* x    = (const float*)d_in[0];
    const float* w    = (const float*)d_in[1];
    const float* bias = (const float*)d_in[2];
    unsigned short* wp = (unsigned short*)d_ws;           // 589,824 B
    float* out = (float*)d_out;

    const size_t NEED = 589824u + 272646144u;             // weights + blurred tensor
    prep_weights<<<1152, 256, 0, stream>>>(w, wp);
    if (ws_size >= NEED) {
        unsigned char* bl = (unsigned char*)d_ws + 589824;
        blur_pre<<<4160, 256, 0, stream>>>(x, bl);
        conv_stage2<<<2048, 512, 0, stream>>>(bl, wp, bias, out);
    } else {
        conv_blur_mfma<<<2048, 512, 0, stream>>>(x, wp, bias, out);
    }
}

// Round 9
// 461.247 us; speedup vs baseline: 1.9654x; 1.2211x over previous
//
#include <hip/hip_runtime.h>

typedef __attribute__((ext_vector_type(8))) short bf16x8;
typedef __attribute__((ext_vector_type(4))) float f32x4;
typedef __attribute__((ext_vector_type(2))) float f32x2;
typedef __attribute__((ext_vector_type(4))) unsigned int u32x4;

static __device__ __forceinline__ unsigned short f2bf(float f) {
    union { float f; unsigned u; } v; v.f = f;
    return (unsigned short)((v.u + 0x7FFFu + ((v.u >> 16) & 1u)) >> 16);
}

// Wp[ch=4][rs=9][oc=256][cw=32] bf16, value = weight[oc][ch*32+cw][r][s] * wscale
__global__ void prep_weights(const float* __restrict__ w, unsigned short* __restrict__ wp) {
    int t = blockIdx.x * 256 + threadIdx.x;      // 0..294911
    const float wscale = 0.02946278254943948f;   // 1/sqrt(3*3*128)
    int cw = t & 31;
    int oc = (t >> 5) & 255;
    int cr = t >> 13;          // 0..35
    int ch = cr / 9;
    int rs = cr - ch * 9;
    int r  = rs / 3;
    int s  = rs - r * 3;
    int c  = ch * 32 + cw;
    wp[t] = f2bf(w[((oc * 128 + c) * 3 + r) * 3 + s] * wscale);
}

// ============ blur_pre v2: fully coalesced, planar channel-pair output ============
// bm[(n*4+cg)*16+chp][t:257][J:256] u32 = 2 bf16 (ch 2chp, 2chp+1); bs[..][t] = J=256 col.
// Lane L handles J in {4L..4L+3} (+J=256 for L=63); wave = one chp; block = 4 chp x 16 rows.
__global__ __launch_bounds__(256, 2)
void blur_pre(const float* __restrict__ x, unsigned* __restrict__ bm, unsigned* __restrict__ bs) {
    const int b = blockIdx.x;          // 4096 = 16 tband x 4 chpg x 4 cg x 16 n
    const int tband = b & 15;
    const int chpg  = (b >> 4) & 3;
    const int cg    = (b >> 6) & 3;
    const int n     = b >> 8;
    const int wv = threadIdx.x >> 6;
    const int L  = threadIdx.x & 63;
    const int chp = chpg * 4 + wv;
    const float* p0 = x + (size_t)(n * 128 + cg * 32 + 2 * chp) * 65536;
    const float* p1 = p0 + 65536;
    const int t0 = tband * 16;
    const int J0 = 4 * L;
    const bool L0 = (L == 0), L63 = (L == 63);
    const int colA = L0 ? 0 : (J0 - 2);
    const int colB = L63 ? 252 : (J0 + 2);
    unsigned* ob = bm + (size_t)((n * 4 + cg) * 16 + chp) * 65792;   // 257*256
    unsigned* os = bs + (size_t)((n * 4 + cg) * 16 + chp) * 257;

    float h0[4][4], h1[4][4], e0[4], e1[4];
    #pragma unroll
    for (int i = 0; i < 20; ++i) {
        const int xr  = t0 - 2 + i;
        const int xrc = xr < 0 ? 0 : (xr > 255 ? 255 : xr);
        const float rm = (xr == xrc) ? 0.125f : 0.f;
        const float* r0 = p0 + (xrc << 8);
        const float* r1 = p1 + (xrc << 8);
        f32x4 rA0, rB0, rA1, rB1;
        __builtin_memcpy(&rA0, r0 + colA, 16);
        __builtin_memcpy(&rB0, r0 + colB, 16);
        __builtin_memcpy(&rA1, r1 + colA, 16);
        __builtin_memcpy(&rB1, r1 + colB, 16);
        // lane-0 / lane-63 window fix-up (branchless)
        const float A0x = L0 ? 0.f : rA0.x, A0y = L0 ? 0.f : rA0.y;
        const float A0z = L0 ? rA0.x : rA0.z, A0w = L0 ? rA0.y : rA0.w;
        const float A1x = L0 ? 0.f : rA1.x, A1y = L0 ? 0.f : rA1.y;
        const float A1z = L0 ? rA1.x : rA1.z, A1w = L0 ? rA1.y : rA1.w;
        const float B0x = L63 ? rB0.z : rB0.x, B0y = L63 ? rB0.w : rB0.y;
        const float B0z = L63 ? 0.f : rB0.z,  B0w = L63 ? 0.f : rB0.w;
        const float B1x = L63 ? rB1.z : rB1.x, B1y = L63 ? rB1.w : rB1.y;
        const float B1z = L63 ? 0.f : rB1.z,  B1w = L63 ? 0.f : rB1.w;
        h0[0][i & 3] = (A0x + 3.f * (A0y + A0z) + A0w) * rm;
        h0[1][i & 3] = (A0y + 3.f * (A0z + A0w) + B0x) * rm;
        h0[2][i & 3] = (A0z + 3.f * (A0w + B0x) + B0y) * rm;
        h0[3][i & 3] = (A0w + 3.f * (B0x + B0y) + B0z) * rm;
        e0[i & 3]    = (B0x + 3.f * B0y) * rm;
        h1[0][i & 3] = (A1x + 3.f * (A1y + A1z) + A1w) * rm;
        h1[1][i & 3] = (A1y + 3.f * (A1z + A1w) + B1x) * rm;
        h1[2][i & 3] = (A1z + 3.f * (A1w + B1x) + B1y) * rm;
        h1[3][i & 3] = (A1w + 3.f * (B1x + B1y) + B1z) * rm;
        e1[i & 3]    = (B1x + 3.f * B1y) * rm;
        if (i >= 3) {
            const int t = t0 + i - 3;          // t0..t0+16 (boundary rows written twice, same value)
            u32x4 o;
            #pragma unroll
            for (int d = 0; d < 4; ++d) {
                float bv0 = (h0[d][(i-3)&3] + 3.f*(h0[d][(i-2)&3] + h0[d][(i-1)&3]) + h0[d][i&3]) * 0.125f;
                float bv1 = (h1[d][(i-3)&3] + 3.f*(h1[d][(i-2)&3] + h1[d][(i-1)&3]) + h1[d][i&3]) * 0.125f;
                o[d] = (unsigned)f2bf(bv0) | ((unsigned)f2bf(bv1) << 16);
            }
            *(u32x4*)(ob + (size_t)t * 256 + J0) = o;
            if (L63) {
                float c0 = (e0[(i-3)&3] + 3.f*(e0[(i-2)&3] + e0[(i-1)&3]) + e0[i&3]) * 0.125f;
                float c1 = (e1[(i-3)&3] + 3.f*(e1[(i-2)&3] + e1[(i-1)&3]) + e1[i&3]) * 0.125f;
                os[t] = (unsigned)f2bf(c0) | ((unsigned)f2bf(c1) << 16);
            }
        }
    }
}

// ---------------- stage 2: MFMA conv over blurred (planar in, LDS transpose) ----------------
#define MF __builtin_amdgcn_mfma_f32_16x16x32_bf16
#define WLOAD(S0, S1, S2, S3, KOFF) {                                          \
    const unsigned short* _wn = wbase + (size_t)(KOFF) * 8192;                 \
    S0 = *(const bf16x8*)(_wn);        S1 = *(const bf16x8*)(_wn + 512);       \
    S2 = *(const bf16x8*)(_wn + 1024); S3 = *(const bf16x8*)(_wn + 1536);      \
}
#define CSTEP(ADRS, R, S0, S1, S2, S3) {                                       \
    const unsigned char* _ab = lds + (ADRS) + (R) * 2112;                      \
    bf16x8 a0 = *(const bf16x8*)(_ab);                                         \
    bf16x8 a1 = *(const bf16x8*)(_ab + 4224);                                  \
    bf16x8 a2 = *(const bf16x8*)(_ab + 8448);                                  \
    bf16x8 a3 = *(const bf16x8*)(_ab + 12672);                                 \
    __builtin_amdgcn_s_setprio(1);                                             \
    acc[0][0]=MF(a0,S0,acc[0][0],0,0,0); acc[0][1]=MF(a0,S1,acc[0][1],0,0,0);  \
    acc[0][2]=MF(a0,S2,acc[0][2],0,0,0); acc[0][3]=MF(a0,S3,acc[0][3],0,0,0);  \
    acc[1][0]=MF(a1,S0,acc[1][0],0,0,0); acc[1][1]=MF(a1,S1,acc[1][1],0,0,0);  \
    acc[1][2]=MF(a1,S2,acc[1][2],0,0,0); acc[1][3]=MF(a1,S3,acc[1][3],0,0,0);  \
    acc[2][0]=MF(a2,S0,acc[2][0],0,0,0); acc[2][1]=MF(a2,S1,acc[2][1],0,0,0);  \
    acc[2][2]=MF(a2,S2,acc[2][2],0,0,0); acc[2][3]=MF(a2,S3,acc[2][3],0,0,0);  \
    acc[3][0]=MF(a3,S0,acc[3][0],0,0,0); acc[3][1]=MF(a3,S1,acc[3][1],0,0,0);  \
    acc[3][2]=MF(a3,S2,acc[3][2],0,0,0); acc[3][3]=MF(a3,S3,acc[3][3],0,0,0);  \
    __builtin_amdgcn_s_setprio(0);                                             \
}
#define CHUNK(BASE, A0,A1,A2,A3, B0,B1,B2,B3)                                  \
    CSTEP(adr0, 0, A0,A1,A2,A3) WLOAD(A0,A1,A2,A3, (BASE)+2)                   \
    CSTEP(adr1, 0, B0,B1,B2,B3) WLOAD(B0,B1,B2,B3, (BASE)+3)                   \
    CSTEP(adr2, 0, A0,A1,A2,A3) WLOAD(A0,A1,A2,A3, (BASE)+4)                   \
    CSTEP(adr0, 1, B0,B1,B2,B3) WLOAD(B0,B1,B2,B3, (BASE)+5)                   \
    CSTEP(adr1, 1, A0,A1,A2,A3) WLOAD(A0,A1,A2,A3, (BASE)+6)                   \
    CSTEP(adr2, 1, B0,B1,B2,B3) WLOAD(B0,B1,B2,B3, (BASE)+7)                   \
    CSTEP(adr0, 2, A0,A1,A2,A3) WLOAD(A0,A1,A2,A3, (BASE)+8)                   \
    CSTEP(adr1, 2, B0,B1,B2,B3) WLOAD(B0,B1,B2,B3, (BASE)+9)                   \
    CSTEP(adr2, 2, A0,A1,A2,A3) WLOAD(A0,A1,A2,A3, (BASE)+10)
#define CHUNK_LAST(BASE, A0,A1,A2,A3, B0,B1,B2,B3)                             \
    CSTEP(adr0, 0, A0,A1,A2,A3) WLOAD(A0,A1,A2,A3, (BASE)+2)                   \
    CSTEP(adr1, 0, B0,B1,B2,B3) WLOAD(B0,B1,B2,B3, (BASE)+3)                   \
    CSTEP(adr2, 0, A0,A1,A2,A3) WLOAD(A0,A1,A2,A3, (BASE)+4)                   \
    CSTEP(adr0, 1, B0,B1,B2,B3) WLOAD(B0,B1,B2,B3, (BASE)+5)                   \
    CSTEP(adr1, 1, A0,A1,A2,A3) WLOAD(A0,A1,A2,A3, (BASE)+6)                   \
    CSTEP(adr2, 1, B0,B1,B2,B3) WLOAD(B0,B1,B2,B3, (BASE)+7)                   \
    CSTEP(adr0, 2, A0,A1,A2,A3) WLOAD(A0,A1,A2,A3, (BASE)+8)                   \
    CSTEP(adr1, 2, B0,B1,B2,B3)                                                \
    CSTEP(adr2, 2, A0,A1,A2,A3)

__global__ __launch_bounds__(512, 2)
void conv_stage2(const unsigned* __restrict__ bm, const unsigned* __restrict__ bs,
                 const unsigned short* __restrict__ wp, const float* __restrict__ bias,
                 float* __restrict__ out) {
    __shared__ __align__(16) unsigned char lds[35904];   // 17 rows x 33 granules x 64B

    const int bx = blockIdx.x;
    const int n  = bx >> 7;
    const int tt = bx & 127;
    const int u0 = (tt >> 3) * 8;
    const int v0 = (tt & 7) * 16;

    const int tid  = threadIdx.x;
    const int lane = tid & 63;
    const int wid  = tid >> 6;
    const int wm   = wid >> 2;       // 0..1
    const int wn   = wid & 3;        // 0..3
    const int g    = lane >> 4;
    const int wq   = lane & 15;

    // ---- staging geometry: 2448 tasks = (row 17 x chp 16) x Jq 9 ----
    unsigned goffm[5], ldsa[5];
    bool act[5], isq8[5], sside[5];
    #pragma unroll
    for (int ii = 0; ii < 5; ++ii) {
        int k = tid + 512 * ii;
        act[ii] = (k < 2448);
        int kk = act[ii] ? k : 0;
        int pr = kk / 9;
        int Jq = kk - 9 * pr;
        int chp = pr & 15;
        int row = pr >> 4;
        int t = 2 * u0 + row;
        isq8[ii]  = (Jq == 8);
        sside[ii] = isq8[ii] && (v0 == 112);
        if (Jq < 8) {
            goffm[ii] = (unsigned)((chp * 257 + t) << 8) + (unsigned)(2 * v0 + 4 * Jq);
            ldsa[ii]  = (unsigned)(row * 2112 + Jq * 256
                       + (((chp >> 2) ^ (Jq & 3)) << 4) + (chp & 3) * 4);
        } else {
            goffm[ii] = sside[ii] ? (unsigned)(chp * 257 + t)
                                  : (unsigned)((chp * 257 + t) << 8) + (unsigned)(2 * v0 + 32);
            ldsa[ii]  = (unsigned)(row * 2112 + 2048 + ((chp >> 2) << 4) + (chp & 3) * 4);
        }
    }
    const unsigned* bmn = bm + (size_t)(n * 4) * 16 * 65792;
    const unsigned* bsn = bs + (size_t)(n * 4) * 16 * 257;
    u32x4 SV[5];

#define STAGE_LOAD(CG) {                                                       \
    const unsigned* _m = bmn + (size_t)(CG) * 16 * 65792;                      \
    const unsigned* _s = bsn + (size_t)(CG) * 16 * 257;                        \
    _Pragma("unroll")                                                          \
    for (int ii = 0; ii < 5; ++ii) {                                           \
        if (act[ii]) {                                                         \
            if (!isq8[ii]) { __builtin_memcpy(&SV[ii], _m + goffm[ii], 16); }  \
            else { SV[ii].x = sside[ii] ? _s[goffm[ii]] : _m[goffm[ii]]; }     \
        }                                                                      \
    }                                                                          \
}
#define STAGE_WRITE() {                                                        \
    _Pragma("unroll")                                                          \
    for (int ii = 0; ii < 5; ++ii) {                                           \
        if (act[ii]) {                                                         \
            if (!isq8[ii]) {                                                   \
                *(unsigned*)(lds + ldsa[ii])       = SV[ii].x;                 \
                *(unsigned*)(lds + ldsa[ii] + 64)  = SV[ii].y;                 \
                *(unsigned*)(lds + ldsa[ii] + 192) = SV[ii].z;                 \
                *(unsigned*)(lds + ldsa[ii] + 128) = SV[ii].w;                 \
            } else {                                                           \
                *(unsigned*)(lds + ldsa[ii]) = SV[ii].x;                       \
            }                                                                  \
        }                                                                      \
    }                                                                          \
}

    // A-frag LDS bases (bj = 2wq + s; granule swizzle J^((J>>1)&1), slot g^((J>>2)&3))
    unsigned adr0, adr1, adr2;
    {
        #pragma unroll
        for (int s = 0; s < 3; ++s) {
            unsigned bj = 2u * (unsigned)wq + (unsigned)s;
            unsigned av = (bj ^ ((bj >> 1) & 1u)) * 64u
                        + (((unsigned)g ^ ((bj >> 2) & 3u)) << 4) + (unsigned)wm * 16896u;
            if (s == 0) adr0 = av; else if (s == 1) adr1 = av; else adr2 = av;
        }
    }

    const unsigned short* wbase = wp + (size_t)(wn * 64 + wq) * 32 + g * 8;
    bf16x8 WA0, WA1, WA2, WA3, WB0, WB1, WB2, WB3;
    WLOAD(WA0, WA1, WA2, WA3, 0)
    WLOAD(WB0, WB1, WB2, WB3, 1)

    f32x4 acc[4][4];
    #pragma unroll
    for (int i = 0; i < 4; ++i)
        #pragma unroll
        for (int j = 0; j < 4; ++j)
            acc[i][j] = (f32x4){0.f, 0.f, 0.f, 0.f};

    STAGE_LOAD(0)
    STAGE_WRITE()
    __syncthreads();
    STAGE_LOAD(1)
    CHUNK(0, WA0, WA1, WA2, WA3, WB0, WB1, WB2, WB3)
    __syncthreads();
    STAGE_WRITE()
    __syncthreads();
    STAGE_LOAD(2)
    CHUNK(9, WB0, WB1, WB2, WB3, WA0, WA1, WA2, WA3)
    __syncthreads();
    STAGE_WRITE()
    __syncthreads();
    STAGE_LOAD(3)
    CHUNK(18, WA0, WA1, WA2, WA3, WB0, WB1, WB2, WB3)
    __syncthreads();
    STAGE_WRITE()
    __syncthreads();
    CHUNK_LAST(27, WB0, WB1, WB2, WB3, WA0, WA1, WA2, WA3)

    // epilogue: u = u0 + wm*4 + mf, v = v0 + 4g + i, oc = wn*64 + nf*16 + wq
    const float gain = 1.4142135623730951f;
    #pragma unroll
    for (int nf = 0; nf < 4; ++nf) {
        const int ocg = wn * 64 + nf * 16 + wq;
        const float bb = bias[ocg];
        #pragma unroll
        for (int mf = 0; mf < 4; ++mf) {
            int u = u0 + wm * 4 + mf;
            f32x4 o;
            #pragma unroll
            for (int i = 0; i < 4; ++i) {
                float z = acc[mf][nf][i] + bb;
                z = (z >= 0.f ? z : 0.2f * z) * gain;
                o[i] = fminf(fmaxf(z, -256.f), 256.f);
            }
            *(f32x4*)(out + (((size_t)n * 256 + ocg) * 128 + u) * 128 + v0 + 4 * g) = o;
        }
    }
}

// ======================= Fallback: proven R5 fused kernel =======================
#define FROW(row) {                                                            \
    int xr  = xr0 + (row);                                                     \
    int xrc = xr < 0 ? 0 : (xr > 255 ? 255 : xr);                              \
    float rm = (xr == xrc) ? 0.125f : 0.0f;                                    \
    const float* p = q + (xrc << 8);                                           \
    f32x4 lo; f32x2 hi;                                                        \
    __builtin_memcpy(&lo, p, 16);                                              \
    __builtin_memcpy(&hi, p + 4, 8);                                           \
    hA[(row) & 3] = (lo.x + 3.f * (lo.y + lo.z) + lo.w) * rm;                  \
    hB[(row) & 3] = (lo.y + 3.f * (lo.z + lo.w) + hi.x) * rm;                  \
    hC[(row) & 3] = (lo.z + 3.f * (lo.w + hi.x) + hi.y) * rm;                  \
}
#define SROW(row) {                                                            \
    int xr = xr0 + (row);                                                      \
    float wv0=0.f,wv1=0.f,wv2=0.f,wv3=0.f,wv4=0.f,wv5=0.f;                     \
    if ((unsigned)xr < 256u) {                                                 \
        const float* p = q + (xr << 8);                                        \
        if ((unsigned)(wc + 0) < 256u) wv0 = p[0];                             \
        if ((unsigned)(wc + 1) < 256u) wv1 = p[1];                             \
        if ((unsigned)(wc + 2) < 256u) wv2 = p[2];                             \
        if ((unsigned)(wc + 3) < 256u) wv3 = p[3];                             \
        if ((unsigned)(wc + 4) < 256u) wv4 = p[4];                             \
        if ((unsigned)(wc + 5) < 256u) wv5 = p[5];                             \
    }                                                                          \
    hA[(row) & 3] = (wv0 + 3.f * (wv1 + wv2) + wv3) * 0.125f;                  \
    hB[(row) & 3] = (wv1 + 3.f * (wv2 + wv3) + wv4) * 0.125f;                  \
    hC[(row) & 3] = (wv2 + 3.f * (wv3 + wv4) + wv5) * 0.125f;                  \
}
#define VROW(row) {                                                            \
    float bv0 = (hA[(row - 3) & 3] + 3.f * (hA[(row - 2) & 3] + hA[(row - 1) & 3]) + hA[(row) & 3]) * 0.125f; \
    float bv1 = (hB[(row - 3) & 3] + 3.f * (hB[(row - 2) & 3] + hB[(row - 1) & 3]) + hB[(row) & 3]) * 0.125f; \
    unsigned rb = (unsigned)(row - 3) * 2640u;                                 \
    *(unsigned short*)(flds + rb + o0) = f2bf(bv0);                            \
    *(unsigned short*)(flds + rb + o1) = f2bf(bv1);                            \
    if (a == 15) {                                                             \
        float bv2 = (hC[(row - 3) & 3] + 3.f * (hC[(row - 2) & 3] + hC[(row - 1) & 3]) + hC[(row) & 3]) * 0.125f; \
        *(unsigned short*)(flds + rb + o2) = f2bf(bv2);                        \
    }                                                                          \
}
__global__ __launch_bounds__(512, 4)
void conv_blur_mfma(const float* __restrict__ x, const unsigned short* __restrict__ wp,
                    const float* __restrict__ bias, float* __restrict__ out) {
    __shared__ __align__(16) unsigned char flds[17 * 33 * 80];
    const int bx = blockIdx.x;
    const int n  = bx >> 7;
    const int tt = bx & 127;
    const int u0 = (tt >> 3) * 8;
    const int v0 = (tt & 7) * 16;
    const int tid  = threadIdx.x;
    const int lane = tid & 63;
    const int wid  = tid >> 6;
    const int wm   = wid >> 2;
    const int wn   = wid & 3;
    const int g    = lane >> 4;
    const int wq   = lane & 15;
    const int a   = tid & 15;
    const int chl = tid >> 4;
    const int wc  = 2 * v0 - 2 + 2 * a;
    const bool edge = (v0 == 0 && a == 0) || (v0 == 112 && a == 15);
    const float* planeBase = x + (size_t)(n * 128 + chl) * 65536;
    const int xr0 = 2 * u0 - 2;
    const unsigned chpart = (unsigned)(((chl >> 1) & 3) * 4 + (chl & 1) * 2);
    const unsigned q4 = (unsigned)(chl >> 3);
    const int c0 = 2 * a;
    const unsigned o0 = (unsigned)(c0 + 0) * 80u + ((q4 ^ (((unsigned)(c0 + 0) >> 3) & 3u)) << 4) + chpart;
    const unsigned o1 = (unsigned)(c0 + 1) * 80u + ((q4 ^ (((unsigned)(c0 + 1) >> 3) & 3u)) << 4) + chpart;
    const unsigned o2 = (unsigned)(c0 + 2) * 80u + ((q4 ^ (((unsigned)(c0 + 2) >> 3) & 3u)) << 4) + chpart;
    const unsigned short* wpL = wp + (size_t)(wn * 64 + wq) * 32 + g * 8;
    f32x4 acc[4][4];
    #pragma unroll
    for (int i = 0; i < 4; ++i)
        #pragma unroll
        for (int j = 0; j < 4; ++j)
            acc[i][j] = (f32x4){0.f, 0.f, 0.f, 0.f};
    for (int ch = 0; ch < 4; ++ch) {
        const float* q = planeBase + (size_t)ch * 32 * 65536 + wc;
        float hA[4], hB[4], hC[4];
        if (!edge) { FROW(0) FROW(1) FROW(2) }
        else       { SROW(0) SROW(1) SROW(2) }
        __syncthreads();
        if (!edge) {
            #pragma unroll
            for (int row = 3; row < 20; ++row) { FROW(row) VROW(row) }
        } else {
            #pragma unroll
            for (int row = 3; row < 20; ++row) { SROW(row) VROW(row) }
        }
        __syncthreads();
        const unsigned short* wpc = wpL + (size_t)ch * 9 * 8192;
        #pragma unroll 1
        for (int r = 0; r < 3; ++r) {
            #pragma unroll 1
            for (int s = 0; s < 3; ++s) {
                bf16x8 b0 = *(const bf16x8*)(wpc + 0 * 512);
                bf16x8 b1 = *(const bf16x8*)(wpc + 1 * 512);
                bf16x8 b2 = *(const bf16x8*)(wpc + 2 * 512);
                bf16x8 b3 = *(const bf16x8*)(wpc + 3 * 512);
                wpc += 8192;
                int bj = 2 * wq + s;
                unsigned cb = (unsigned)bj * 80u + ((unsigned)(g ^ ((bj >> 3) & 3)) << 4);
                #pragma unroll
                for (int mf = 0; mf < 4; ++mf) {
                    int bi = 2 * (wm * 4 + mf) + r;
                    bf16x8 afrag = *(const bf16x8*)(flds + (unsigned)bi * 2640u + cb);
                    acc[mf][0] = MF(afrag, b0, acc[mf][0], 0, 0, 0);
                    acc[mf][1] = MF(afrag, b1, acc[mf][1], 0, 0, 0);
                    acc[mf][2] = MF(afrag, b2, acc[mf][2], 0, 0, 0);
                    acc[mf][3] = MF(afrag, b3, acc[mf][3], 0, 0, 0);
                }
            }
        }
    }
    const float gain = 1.4142135623730951f;
    #pragma unroll
    for (int nf = 0; nf < 4; ++nf) {
        int ocg = wn * 64 + nf * 16 + wq;
        float bv = bias[ocg];
        #pragma unroll
        for (int mf = 0; mf < 4; ++mf) {
            int u = u0 + wm * 4 + mf;
            f32x4 o;
            #pragma unroll
            for (int i = 0; i < 4; ++i) {
                float z = acc[mf][nf][i] + bv;
                z = (z >= 0.f ? z : 0.2f * z) * gain;
                o[i] = fminf(fmaxf(z, -256.f), 256.f);
            }
            *(f32x4*)(out + (((size_t)n * 256 + ocg) * 128 + u) * 128 + v0 + 4 * g) = o;
        }
    }
}

extern "C" void kernel_launch(void* const* d_in, const int* in_sizes, int n_in,
                              void* d_out, int out_size, void* d_ws, size_t ws_size,
                              hipStream_t stream) {
    const float* x    = (const float*)d_in[0];
    const float* w    = (const float*)d_in[1];
    const float* bias = (const float*)d_in[2];
    unsigned short* wp = (unsigned short*)d_ws;           // 589,824 B
    float* out = (float*)d_out;

    const size_t BM_BYTES = 269484032u;                   // 1024 * 257*256 * 4
    const size_t BS_BYTES = 1052672u;                     // 1024 * 257 * 4
    const size_t NEED = 589824u + BM_BYTES + BS_BYTES;    // 271,126,528
    prep_weights<<<1152, 256, 0, stream>>>(w, wp);
    if (ws_size >= NEED) {
        unsigned* bm = (unsigned*)((unsigned char*)d_ws + 589824);
        unsigned* bs = (unsigned*)((unsigned char*)d_ws + 589824 + BM_BYTES);
        blur_pre<<<4096, 256, 0, stream>>>(x, bm, bs);
        conv_stage2<<<2048, 512, 0, stream>>>(bm, bs, wp, bias, out);
    } else {
        conv_blur_mfma<<<2048, 512, 0, stream>>>(x, wp, bias, out);
    }
}